// Round 6
// baseline (225.165 us; speedup 1.0000x reference)
//
#include <hip/hip_runtime.h>
#include <math.h>

#define FEAT 64
#define NKERN 3

typedef __attribute__((ext_vector_type(8))) short short8;
typedef __attribute__((ext_vector_type(4))) float float4v;
typedef __attribute__((ext_vector_type(2))) float float2v;

__device__ __forceinline__ unsigned short f2bf(float f) {
    unsigned int u = __float_as_uint(f);
    u = (u + 0x7fffu + ((u >> 16) & 1u)) >> 16;   // round-to-nearest-even
    return (unsigned short)u;
}
__device__ __forceinline__ float bf2f(unsigned short b) {
    return __uint_as_float(((unsigned int)b) << 16);
}
// fast tanh: 1 - 2/(e^{2x}+1), exact at +-inf, bf16-level accurate
__device__ __forceinline__ float fast_tanh(float x) {
    float e = __expf(2.f * x);
    return fmaf(-2.f, __builtin_amdgcn_rcpf(e + 1.f), 1.f);
}

// Combined prep: feat fp32->bf16 cast (first nCastBlocks) + fcW frag-tiling.
__global__ __launch_bounds__(256) void prep_kernel(
    const float* __restrict__ x, unsigned short* __restrict__ y, int n4,
    const float* __restrict__ fcW,
    unsigned short* __restrict__ Bth, unsigned short* __restrict__ Btl,
    int totalW, int nCastBlocks)
{
    int b = blockIdx.x;
    if (b < nCastBlocks) {
        int i = b * 256 + threadIdx.x;
        if (i >= n4) return;
        float4 v = ((const float4*)x)[i];
        ushort4 o;
        o.x = f2bf(v.x); o.y = f2bf(v.y); o.z = f2bf(v.z); o.w = f2bf(v.w);
        ((ushort4*)y)[i] = o;
    } else {
        int idx = (b - nCastBlocks) * 256 + threadIdx.x;
        if (idx >= totalW) return;
        int l   = idx / (FEAT * 192);
        int rem = idx - l * (FEAT * 192);
        int f   = rem / 192;
        int jp  = rem - f * 192;
        int k = jp >> 6, j = jp & 63;
        float v = fcW[(size_t)l * 12288 + j * 192 + k * 64 + f];
        unsigned short hi = f2bf(v);
        int dst = l * 12288 +
                  ((((f >> 4) * 6 + (jp >> 5)) * 4 + ((jp >> 3) & 3)) * 16 + (f & 15)) * 8 +
                  (jp & 7);
        Bth[dst] = hi;
        Btl[dst] = f2bf(v - bf2f(hi));
    }
}

// One fused layer, PERSISTENT blocks: grid = 1536 (6 blocks/CU resident at
// launch_bounds(256,6)); each block grid-strides over node tiles (~2 each).
// Eliminates block launch/drain churn (3125 short blocks -> 12/CU serial was
// the remaining theory after VALU/ILP/occupancy-request changes were neutral)
// and amortizes per-block setup (layer constants, bases) across tiles.
// Per tile (verified structure from prior rounds, unchanged):
//   Phase 1 step A: lane = (node=half, edge=p); per-edge Gaussian weights;
//     16B LDS record [cc<<7, w0, w1, w2] per edge, all 4 nodes/wave.
//   Phase 1 step B: combined loop over 32 edges, both node-pairs interleaved
//     (2 independent ds_read->gather->FMA chains, unroll 4).
//   Phase 2: ALL 4 waves MFMA (wave = f-tile), Bt hi/lo from L2.
__global__ __launch_bounds__(256, 6) void layer_kernel(
    const unsigned short* __restrict__ h,    // [N, 64] bf16
    const int*   __restrict__ rowptr,        // [N+1]
    const int*   __restrict__ colind,        // [E]
    const float* __restrict__ pseudo,        // [E, 2]
    const float* __restrict__ projW,         // [L, 2, 2]
    const float* __restrict__ projB,         // [L, 2]
    const float* __restrict__ mu,            // [L, 3, 2]
    const float* __restrict__ isg,           // [L, 3, 2]
    int layer,
    const unsigned short* __restrict__ Bth,  // frag-tiled, this layer
    const unsigned short* __restrict__ Btl,
    float* __restrict__ out,                 // [N,64] fp32 (last layer)
    unsigned short* __restrict__ hnext,      // [N,64] bf16 (mid layers)
    int n_nodes, int last_layer, int ntiles)
{
    __shared__ __align__(16) unsigned short Atile[3264];     // 6 ks * 544 shorts
    __shared__ __align__(16) unsigned int   Wlds[4][4][128]; // 4 waves x 4 node-slots
    int tid  = threadIdx.x;
    int wv   = tid >> 6;
    int lane = tid & 63;

    // per-layer constants (uniform s_loads, once per BLOCK, amortized over tiles)
    const float* pw = projW + layer * 4;
    const float* pb = projB + layer * 2;
    const float* mm = mu  + layer * 6;
    const float* ss = isg + layer * 6;
    float pw0 = pw[0], pw1 = pw[1], pw2 = pw[2], pw3 = pw[3];
    float pb0 = pb[0], pb1 = pb[1];
    float m0 = mm[0], m1 = mm[1], m2 = mm[2], m3 = mm[3], m4 = mm[4], m5 = mm[5];
    float c0 = -0.5f * ss[0] * ss[0], c1 = -0.5f * ss[1] * ss[1];
    float c2 = -0.5f * ss[2] * ss[2], c3 = -0.5f * ss[3] * ss[3];
    float c4 = -0.5f * ss[4] * ss[4], c5 = -0.5f * ss[5] * ss[5];

    int half = lane >> 5;
    int p    = lane & 31;
    unsigned int featoff = (unsigned int)(p * 4);   // byte off of feat pair in bf16 row
    const char* hb = (const char*)h;

    // B-frag pointers (per-block invariant)
    int q  = lane >> 4;
    int nn = lane & 15;
    const unsigned short* bt0 = Bth + (((wv * 6) * 4 + q) * 16 + nn) * 8;
    const unsigned short* bt1 = Btl + (((wv * 6) * 4 + q) * 16 + nn) * 8;

    for (int t = blockIdx.x; t < ntiles; t += gridDim.x) {
        if (t != (int)blockIdx.x) __syncthreads();   // Atile reuse vs prev phase 2
        int t0 = t * 16;

        // ---- Step A: per-edge records for ALL 4 nodes of this wave ----
        bool fastp[2];
        #pragma unroll
        for (int tt = 0; tt < 2; ++tt) {
            int node = t0 + wv * 4 + tt * 2 + half;
            int ncl  = node < n_nodes - 1 ? node : (n_nodes - 1);
            int rp   = rowptr[ncl];
            int deg  = rowptr[ncl + 1] - rp;
            bool fast = __all((deg == 32) && (node < n_nodes));
            fastp[tt] = fast;
            if (fast) {
                int ei = rp + p;
                int cc = colind[ei];                       // coalesced dword
                float2 ps = ((const float2*)pseudo)[ei];   // coalesced 8B
                float u0 = fast_tanh(fmaf(ps.x, pw0, fmaf(ps.y, pw2, pb0)));
                float u1 = fast_tanh(fmaf(ps.x, pw1, fmaf(ps.y, pw3, pb1)));
                float d0 = u0 - m0, d1 = u1 - m1;
                float w0v = __expf(fmaf(d0 * d0, c0, d1 * d1 * c1));
                d0 = u0 - m2; d1 = u1 - m3;
                float w1v = __expf(fmaf(d0 * d0, c2, d1 * d1 * c3));
                d0 = u0 - m4; d1 = u1 - m5;
                float w2v = __expf(fmaf(d0 * d0, c4, d1 * d1 * c5));
                uint4 recw;
                recw.x = ((unsigned int)cc) << 7;          // byte offset of row
                recw.y = __float_as_uint(w0v);
                recw.z = __float_as_uint(w1v);
                recw.w = __float_as_uint(w2v);
                *(uint4*)&Wlds[wv][tt * 2 + half][p * 4] = recw;  // ds_write_b128
            }
        }

        if (fastp[0] && fastp[1]) {
            // ---- Step B: combined loop, 2 independent chains (pair0, pair1) ----
            const unsigned int* WA = &Wlds[wv][half][0];       // pair0, slot half
            const unsigned int* WB = &Wlds[wv][2 + half][0];   // pair1, slot 2+half
            float2v aA0 = {0.f, 0.f}, aA1 = {0.f, 0.f}, aA2 = {0.f, 0.f};
            float2v aB0 = {0.f, 0.f}, aB1 = {0.f, 0.f}, aB2 = {0.f, 0.f};
            #pragma unroll 4
            for (int i = 0; i < 32; ++i) {
                uint4 rA = *(const uint4*)(WA + i * 4);    // ds_read_b128 broadcast
                uint4 rB = *(const uint4*)(WB + i * 4);
                unsigned int hA = *(const unsigned int*)(hb + (rA.x + featoff));
                unsigned int hB = *(const unsigned int*)(hb + (rB.x + featoff));
                float2v vA, vB;
                vA.x = __uint_as_float(hA << 16);
                vA.y = __uint_as_float(hA & 0xffff0000u);
                vB.x = __uint_as_float(hB << 16);
                vB.y = __uint_as_float(hB & 0xffff0000u);
                float wA0 = __uint_as_float(rA.y), wA1 = __uint_as_float(rA.z), wA2 = __uint_as_float(rA.w);
                float wB0 = __uint_as_float(rB.y), wB1 = __uint_as_float(rB.z), wB2 = __uint_as_float(rB.w);
#if __has_builtin(__builtin_elementwise_fma)
                float2v sA0 = {wA0, wA0}, sA1 = {wA1, wA1}, sA2 = {wA2, wA2};
                float2v sB0 = {wB0, wB0}, sB1 = {wB1, wB1}, sB2 = {wB2, wB2};
                aA0 = __builtin_elementwise_fma(vA, sA0, aA0);
                aA1 = __builtin_elementwise_fma(vA, sA1, aA1);
                aA2 = __builtin_elementwise_fma(vA, sA2, aA2);
                aB0 = __builtin_elementwise_fma(vB, sB0, aB0);
                aB1 = __builtin_elementwise_fma(vB, sB1, aB1);
                aB2 = __builtin_elementwise_fma(vB, sB2, aB2);
#else
                aA0.x = fmaf(vA.x, wA0, aA0.x); aA0.y = fmaf(vA.y, wA0, aA0.y);
                aA1.x = fmaf(vA.x, wA1, aA1.x); aA1.y = fmaf(vA.y, wA1, aA1.y);
                aA2.x = fmaf(vA.x, wA2, aA2.x); aA2.y = fmaf(vA.y, wA2, aA2.y);
                aB0.x = fmaf(vB.x, wB0, aB0.x); aB0.y = fmaf(vB.y, wB0, aB0.y);
                aB1.x = fmaf(vB.x, wB1, aB1.x); aB1.y = fmaf(vB.y, wB1, aB1.y);
                aB2.x = fmaf(vB.x, wB2, aB2.x); aB2.y = fmaf(vB.y, wB2, aB2.y);
#endif
            }
            // ---- epilogue: pack 2 feats -> dword, A-frag layout (verified) ----
            int j0 = p * 2;
            int sa = (j0 >> 5) * 544 + ((j0 >> 3) & 3) * 136 + (j0 & 7);
            int sa0 = sa + (wv * 4 + half) * 8;        // pair0 row m
            int sa1 = sa + (wv * 4 + 2 + half) * 8;    // pair1 row m
            unsigned int k0, k1, k2, k3, k4, k5;
            asm("v_cvt_pk_bf16_f32 %0, %1, %2" : "=v"(k0) : "v"(aA0.x), "v"(aA0.y));
            asm("v_cvt_pk_bf16_f32 %0, %1, %2" : "=v"(k1) : "v"(aA1.x), "v"(aA1.y));
            asm("v_cvt_pk_bf16_f32 %0, %1, %2" : "=v"(k2) : "v"(aA2.x), "v"(aA2.y));
            asm("v_cvt_pk_bf16_f32 %0, %1, %2" : "=v"(k3) : "v"(aB0.x), "v"(aB0.y));
            asm("v_cvt_pk_bf16_f32 %0, %1, %2" : "=v"(k4) : "v"(aB1.x), "v"(aB1.y));
            asm("v_cvt_pk_bf16_f32 %0, %1, %2" : "=v"(k5) : "v"(aB2.x), "v"(aB2.y));
            *(unsigned int*)&Atile[sa0]        = k0;
            *(unsigned int*)&Atile[sa0 + 1088] = k1;
            *(unsigned int*)&Atile[sa0 + 2176] = k2;
            *(unsigned int*)&Atile[sa1]        = k3;
            *(unsigned int*)&Atile[sa1 + 1088] = k4;
            *(unsigned int*)&Atile[sa1 + 2176] = k5;
        } else {
            // generic serial path (tail / irregular degree; never hot here)
            for (int mq = 0; mq < 4; ++mq) {
                int node = t0 + wv * 4 + mq;
                float a0 = 0.f, a1 = 0.f, a2 = 0.f;
                if (node < n_nodes) {
                    int nu = __builtin_amdgcn_readfirstlane(node);
                    int r0 = rowptr[nu];
                    int dg = rowptr[nu + 1] - r0;
                    for (int i = 0; i < dg; ++i) {
                        int cc = colind[r0 + i];
                        float px = pseudo[(size_t)(r0 + i) * 2];
                        float py = pseudo[(size_t)(r0 + i) * 2 + 1];
                        float u0 = fast_tanh(fmaf(px, pw0, fmaf(py, pw2, pb0)));
                        float u1 = fast_tanh(fmaf(px, pw1, fmaf(py, pw3, pb1)));
                        float d0 = u0 - m0, d1 = u1 - m1;
                        float w0e = __expf(fmaf(d0 * d0, c0, d1 * d1 * c1));
                        d0 = u0 - m2; d1 = u1 - m3;
                        float w1e = __expf(fmaf(d0 * d0, c2, d1 * d1 * c3));
                        d0 = u0 - m4; d1 = u1 - m5;
                        float w2e = __expf(fmaf(d0 * d0, c4, d1 * d1 * c5));
                        float vf = bf2f(h[(size_t)cc * FEAT + lane]);
                        a0 = fmaf(w0e, vf, a0);
                        a1 = fmaf(w1e, vf, a1);
                        a2 = fmaf(w2e, vf, a2);
                    }
                }
                int sb = (lane >> 5) * 544 + ((lane >> 3) & 3) * 136 + (wv * 4 + mq) * 8 + (lane & 7);
                Atile[sb]        = f2bf(a0);
                Atile[sb + 1088] = f2bf(a1);
                Atile[sb + 2176] = f2bf(a2);
            }
        }
        __syncthreads();

        // Phase 2: wave wv = f-tile; B hi/lo frags from pre-tiled, L2-resident Bt.
        float4v acc = (float4v){0.f, 0.f, 0.f, 0.f};
        #pragma unroll
        for (int ks = 0; ks < 6; ++ks) {
            short8 ah = *(const short8*)&Atile[ks * 544 + q * 136 + nn * 8];
            short8 bh = *(const short8*)(bt0 + ks * 512);
            short8 bl = *(const short8*)(bt1 + ks * 512);
            acc = __builtin_amdgcn_mfma_f32_16x16x32_bf16(ah, bh, acc, 0, 0, 0);
            acc = __builtin_amdgcn_mfma_f32_16x16x32_bf16(ah, bl, acc, 0, 0, 0);
        }
        // D: col f = wv*16+nn, row = t0 + q*4 + r
        #pragma unroll
        for (int r = 0; r < 4; ++r) {
            int row = t0 + q * 4 + r;
            if (row < n_nodes) {
                if (last_layer)
                    out[(size_t)row * 64 + wv * 16 + nn] = acc[r];
                else
                    hnext[(size_t)row * 64 + wv * 16 + nn] = f2bf(acc[r]);
            }
        }
    }
}

extern "C" void kernel_launch(void* const* d_in, const int* in_sizes, int n_in,
                              void* d_out, int out_size, void* d_ws, size_t ws_size,
                              hipStream_t stream)
{
    const float* feat   = (const float*)d_in[0];   // [N, 64]
    const float* pseudo = (const float*)d_in[1];   // [E, 2]
    const int*   rowptr = (const int*)d_in[2];     // [N+1]
    const int*   colind = (const int*)d_in[3];     // [E]
    const float* projW  = (const float*)d_in[4];   // [L, 2, 2]
    const float* projB  = (const float*)d_in[5];   // [L, 2]
    const float* fcW    = (const float*)d_in[6];   // [L, 64, 192]
    const float* mu     = (const float*)d_in[7];   // [L, 3, 2]
    const float* isg    = (const float*)d_in[8];   // [L, 3, 2]
    float* out = (float*)d_out;

    int n  = in_sizes[0] / FEAT;                        // 50000
    int n_layers = in_sizes[6] / (FEAT * NKERN * FEAT); // 3

    unsigned short* hbA = (unsigned short*)d_ws;                  // n*64
    unsigned short* hbB = hbA + (size_t)n * FEAT;                 // n*64
    unsigned short* Bth = hbB + (size_t)n * FEAT;                 // L*12288
    unsigned short* Btl = Bth + (size_t)n_layers * 12288;         // L*12288

    int n4 = n * FEAT / 4;
    int totalW = n_layers * FEAT * 192;
    int castBlocks = (n4 + 255) / 256;
    int wpBlocks   = (totalW + 255) / 256;

    int ntiles = (n + 15) / 16;
    int gblocks = ntiles < 1536 ? ntiles : 1536;   // 6 blocks/CU resident

    dim3 blk(256);
    dim3 prepGrid(castBlocks + wpBlocks);
    dim3 layerGrid(gblocks);
    dim3 layerBlk(256);

    prep_kernel<<<prepGrid, blk, 0, stream>>>(
        feat, hbA, n4, fcW, Bth, Btl, totalW, castBlocks);

    const unsigned short* hin = hbA;
    for (int l = 0; l < n_layers; ++l) {
        int last = (l == n_layers - 1);
        unsigned short* hb_out = (l == 0) ? hbB : hbA;
        layer_kernel<<<layerGrid, layerBlk, 0, stream>>>(
            hin, rowptr, colind, pseudo, projW, projB, mu, isg, l,
            Bth + (size_t)l * 12288, Btl + (size_t)l * 12288,
            out, hb_out, n, last, ntiles);
        hin = hb_out;
    }
}

// Round 7
// 167.003 us; speedup vs baseline: 1.3483x; 1.3483x over previous
//
#include <hip/hip_runtime.h>
#include <math.h>

#define FEAT 64
#define NKERN 3

typedef __attribute__((ext_vector_type(8))) short short8;
typedef __attribute__((ext_vector_type(4))) float float4v;
typedef __attribute__((ext_vector_type(2))) float float2v;

__device__ __forceinline__ unsigned short f2bf(float f) {
    unsigned int u = __float_as_uint(f);
    u = (u + 0x7fffu + ((u >> 16) & 1u)) >> 16;   // round-to-nearest-even
    return (unsigned short)u;
}
__device__ __forceinline__ float bf2f(unsigned short b) {
    return __uint_as_float(((unsigned int)b) << 16);
}
// fast tanh: 1 - 2/(e^{2x}+1), exact at +-inf, bf16-level accurate
__device__ __forceinline__ float fast_tanh(float x) {
    float e = __expf(2.f * x);
    return fmaf(-2.f, __builtin_amdgcn_rcpf(e + 1.f), 1.f);
}

// Combined prep: feat fp32->bf16 cast (first nCastBlocks) + fcW frag-tiling.
__global__ __launch_bounds__(256) void prep_kernel(
    const float* __restrict__ x, unsigned short* __restrict__ y, int n4,
    const float* __restrict__ fcW,
    unsigned short* __restrict__ Bth, unsigned short* __restrict__ Btl,
    int totalW, int nCastBlocks)
{
    int b = blockIdx.x;
    if (b < nCastBlocks) {
        int i = b * 256 + threadIdx.x;
        if (i >= n4) return;
        float4 v = ((const float4*)x)[i];
        ushort4 o;
        o.x = f2bf(v.x); o.y = f2bf(v.y); o.z = f2bf(v.z); o.w = f2bf(v.w);
        ((ushort4*)y)[i] = o;
    } else {
        int idx = (b - nCastBlocks) * 256 + threadIdx.x;
        if (idx >= totalW) return;
        int l   = idx / (FEAT * 192);
        int rem = idx - l * (FEAT * 192);
        int f   = rem / 192;
        int jp  = rem - f * 192;
        int k = jp >> 6, j = jp & 63;
        float v = fcW[(size_t)l * 12288 + j * 192 + k * 64 + f];
        unsigned short hi = f2bf(v);
        int dst = l * 12288 +
                  ((((f >> 4) * 6 + (jp >> 5)) * 4 + ((jp >> 3) & 3)) * 16 + (f & 15)) * 8 +
                  (jp & 7);
        Bth[dst] = hi;
        Btl[dst] = f2bf(v - bf2f(hi));
    }
}

// One fused layer: block = 4 waves = 256 threads, tile = 16 nodes, 1 tile/block.
// Phase 1 step A: lane = (node=half, edge=p); per-edge Gaussian weights;
//   16B LDS record [cc<<7, w0, w1, w2] per edge, 4 node-slots per wave
//   (slot stride padded to 528B -> the 4-address rec broadcast in step B is
//   bank-conflict-free).
// Phase 1 step B (THE FIX): lane = (node g=lane>>4, featquad p4=lane&15).
//   Explicitly software-pipelined with NAMED register arrays so the register
//   allocator must keep 4 recs + 4 gathers in flight (prior rounds: VGPR=32-40
//   => compiler serialized ds_read->wait->gather->wait per edge; 64 x ~900cy
//   = the measured 60K cy/tile wall). Per batch of 4 edges: 4 dwordx2 gathers
//   (each instr covers all 4 nodes = 4 x 128B segments) issued, next batch's
//   4 ds_read_b128 recs issued, then consume. 16 lines in flight per wave.
// Phase 2: ALL 4 waves MFMA (wave = f-tile), unchanged (verified).
__global__ __launch_bounds__(256, 4) void layer_kernel(
    const unsigned short* __restrict__ h,    // [N, 64] bf16
    const int*   __restrict__ rowptr,        // [N+1]
    const int*   __restrict__ colind,        // [E]
    const float* __restrict__ pseudo,        // [E, 2]
    const float* __restrict__ projW,         // [L, 2, 2]
    const float* __restrict__ projB,         // [L, 2]
    const float* __restrict__ mu,            // [L, 3, 2]
    const float* __restrict__ isg,           // [L, 3, 2]
    int layer,
    const unsigned short* __restrict__ Bth,  // frag-tiled, this layer
    const unsigned short* __restrict__ Btl,
    float* __restrict__ out,                 // [N,64] fp32 (last layer)
    unsigned short* __restrict__ hnext,      // [N,64] bf16 (mid layers)
    int n_nodes, int last_layer)
{
    __shared__ __align__(16) unsigned short Atile[3264];     // 6 ks * 544 shorts
    __shared__ __align__(16) unsigned int   Wlds[4][4][132]; // padded: slot stride 528B
    int tid  = threadIdx.x;
    int wv   = tid >> 6;
    int lane = tid & 63;
    int t0   = blockIdx.x * 16;

    // per-layer constants (uniform s_loads, once)
    const float* pw = projW + layer * 4;
    const float* pb = projB + layer * 2;
    const float* mm = mu  + layer * 6;
    const float* ss = isg + layer * 6;
    float pw0 = pw[0], pw1 = pw[1], pw2 = pw[2], pw3 = pw[3];
    float pb0 = pb[0], pb1 = pb[1];
    float m0 = mm[0], m1 = mm[1], m2 = mm[2], m3 = mm[3], m4 = mm[4], m5 = mm[5];
    float c0 = -0.5f * ss[0] * ss[0], c1 = -0.5f * ss[1] * ss[1];
    float c2 = -0.5f * ss[2] * ss[2], c3 = -0.5f * ss[3] * ss[3];
    float c4 = -0.5f * ss[4] * ss[4], c5 = -0.5f * ss[5] * ss[5];

    int half = lane >> 5;
    int p    = lane & 31;
    const char* hb = (const char*)h;

    // ---- Step A: per-edge records for ALL 4 nodes of this wave ----
    bool fastp[2];
    #pragma unroll
    for (int tt = 0; tt < 2; ++tt) {
        int node = t0 + wv * 4 + tt * 2 + half;
        int ncl  = node < n_nodes - 1 ? node : (n_nodes - 1);
        int rp   = rowptr[ncl];
        int deg  = rowptr[ncl + 1] - rp;
        bool fast = __all((deg == 32) && (node < n_nodes));
        fastp[tt] = fast;
        if (fast) {
            int ei = rp + p;
            int cc = colind[ei];                       // coalesced dword
            float2 ps = ((const float2*)pseudo)[ei];   // coalesced 8B
            float u0 = fast_tanh(fmaf(ps.x, pw0, fmaf(ps.y, pw2, pb0)));
            float u1 = fast_tanh(fmaf(ps.x, pw1, fmaf(ps.y, pw3, pb1)));
            float d0 = u0 - m0, d1 = u1 - m1;
            float w0v = __expf(fmaf(d0 * d0, c0, d1 * d1 * c1));
            d0 = u0 - m2; d1 = u1 - m3;
            float w1v = __expf(fmaf(d0 * d0, c2, d1 * d1 * c3));
            d0 = u0 - m4; d1 = u1 - m5;
            float w2v = __expf(fmaf(d0 * d0, c4, d1 * d1 * c5));
            uint4 recw;
            recw.x = ((unsigned int)cc) << 7;          // byte offset of row
            recw.y = __float_as_uint(w0v);
            recw.z = __float_as_uint(w1v);
            recw.w = __float_as_uint(w2v);
            *(uint4*)&Wlds[wv][tt * 2 + half][p * 4] = recw;  // ds_write_b128
        }
    }

    if (fastp[0] && fastp[1]) {
        // ---- Step B: lane = (node g, featquad p4), explicit 4-deep pipeline ----
        int g  = lane >> 4;        // node slot 0..3
        int p4 = lane & 15;        // feat quad: feats 4*p4 .. 4*p4+3
        unsigned int fo4 = (unsigned int)(p4 * 8);   // byte offset in 128B row
        const unsigned int* Wg = &Wlds[wv][g][0];

        float2v a0l = {0.f,0.f}, a0h = {0.f,0.f};
        float2v a1l = {0.f,0.f}, a1h = {0.f,0.f};
        float2v a2l = {0.f,0.f}, a2h = {0.f,0.f};

        uint4 r0 = *(const uint4*)(Wg + 0);
        uint4 r1 = *(const uint4*)(Wg + 4);
        uint4 r2 = *(const uint4*)(Wg + 8);
        uint4 r3 = *(const uint4*)(Wg + 12);

        #pragma unroll
        for (int b = 0; b < 8; ++b) {
            // issue 4 gathers (each instr: 4 nodes x 128B contiguous segments)
            uint2 h0 = *(const uint2*)(hb + (r0.x + fo4));
            uint2 h1 = *(const uint2*)(hb + (r1.x + fo4));
            uint2 h2 = *(const uint2*)(hb + (r2.x + fo4));
            uint2 h3 = *(const uint2*)(hb + (r3.x + fo4));
            // issue next batch's recs (ds_read) while gathers are in flight
            uint4 n0, n1, n2, n3;
            if (b < 7) {
                n0 = *(const uint4*)(Wg + (b + 1) * 16 + 0);
                n1 = *(const uint4*)(Wg + (b + 1) * 16 + 4);
                n2 = *(const uint4*)(Wg + (b + 1) * 16 + 8);
                n3 = *(const uint4*)(Wg + (b + 1) * 16 + 12);
            }
            // consume (compiler inserts vmcnt waits here, after all issues)
#define CONSUME(hv, rc) do {                                                   \
            float2v vlo, vhi;                                                  \
            vlo.x = __uint_as_float((hv).x << 16);                             \
            vlo.y = __uint_as_float((hv).x & 0xffff0000u);                     \
            vhi.x = __uint_as_float((hv).y << 16);                             \
            vhi.y = __uint_as_float((hv).y & 0xffff0000u);                     \
            float w0 = __uint_as_float((rc).y);                                \
            float w1 = __uint_as_float((rc).z);                                \
            float w2 = __uint_as_float((rc).w);                                \
            float2v s0 = {w0, w0}, s1 = {w1, w1}, s2 = {w2, w2};               \
            a0l = __builtin_elementwise_fma(vlo, s0, a0l);                     \
            a0h = __builtin_elementwise_fma(vhi, s0, a0h);                     \
            a1l = __builtin_elementwise_fma(vlo, s1, a1l);                     \
            a1h = __builtin_elementwise_fma(vhi, s1, a1h);                     \
            a2l = __builtin_elementwise_fma(vlo, s2, a2l);                     \
            a2h = __builtin_elementwise_fma(vhi, s2, a2h);                     \
        } while (0)
            CONSUME(h0, r0);
            CONSUME(h1, r1);
            CONSUME(h2, r2);
            CONSUME(h3, r3);
#undef CONSUME
            if (b < 7) { r0 = n0; r1 = n1; r2 = n2; r3 = n3; }
        }

        // ---- epilogue: pack 4 feats -> 2 dwords, A-frag layout (verified) ----
        int m  = wv * 4 + g;
        int j0 = p4 * 4;   // j0&7 in {0,4}: quad stays inside one 8-short group
        int sa = (j0 >> 5) * 544 + ((j0 >> 3) & 3) * 136 + m * 8 + (j0 & 7);
        unsigned int k0l, k0h, k1l, k1h, k2l, k2h;
        asm("v_cvt_pk_bf16_f32 %0, %1, %2" : "=v"(k0l) : "v"(a0l.x), "v"(a0l.y));
        asm("v_cvt_pk_bf16_f32 %0, %1, %2" : "=v"(k0h) : "v"(a0h.x), "v"(a0h.y));
        asm("v_cvt_pk_bf16_f32 %0, %1, %2" : "=v"(k1l) : "v"(a1l.x), "v"(a1l.y));
        asm("v_cvt_pk_bf16_f32 %0, %1, %2" : "=v"(k1h) : "v"(a1h.x), "v"(a1h.y));
        asm("v_cvt_pk_bf16_f32 %0, %1, %2" : "=v"(k2l) : "v"(a2l.x), "v"(a2l.y));
        asm("v_cvt_pk_bf16_f32 %0, %1, %2" : "=v"(k2h) : "v"(a2h.x), "v"(a2h.y));
        uint2 w0 = {k0l, k0h}, w1 = {k1l, k1h}, w2 = {k2l, k2h};
        *(uint2*)&Atile[sa]        = w0;   // 8B aligned: sa%4==0 (j0&7 in {0,4})
        *(uint2*)&Atile[sa + 1088] = w1;
        *(uint2*)&Atile[sa + 2176] = w2;
    } else {
        // generic serial path (tail / irregular degree; never hot here)
        for (int mq = 0; mq < 4; ++mq) {
            int node = t0 + wv * 4 + mq;
            float a0 = 0.f, a1 = 0.f, a2 = 0.f;
            if (node < n_nodes) {
                int nu = __builtin_amdgcn_readfirstlane(node);
                int r0 = rowptr[nu];
                int dg = rowptr[nu + 1] - r0;
                for (int i = 0; i < dg; ++i) {
                    int cc = colind[r0 + i];
                    float px = pseudo[(size_t)(r0 + i) * 2];
                    float py = pseudo[(size_t)(r0 + i) * 2 + 1];
                    float u0 = fast_tanh(fmaf(px, pw0, fmaf(py, pw2, pb0)));
                    float u1 = fast_tanh(fmaf(px, pw1, fmaf(py, pw3, pb1)));
                    float d0 = u0 - m0, d1 = u1 - m1;
                    float w0e = __expf(fmaf(d0 * d0, c0, d1 * d1 * c1));
                    d0 = u0 - m2; d1 = u1 - m3;
                    float w1e = __expf(fmaf(d0 * d0, c2, d1 * d1 * c3));
                    d0 = u0 - m4; d1 = u1 - m5;
                    float w2e = __expf(fmaf(d0 * d0, c4, d1 * d1 * c5));
                    float vf = bf2f(h[(size_t)cc * FEAT + lane]);
                    a0 = fmaf(w0e, vf, a0);
                    a1 = fmaf(w1e, vf, a1);
                    a2 = fmaf(w2e, vf, a2);
                }
            }
            int sb = (lane >> 5) * 544 + ((lane >> 3) & 3) * 136 + (wv * 4 + mq) * 8 + (lane & 7);
            Atile[sb]        = f2bf(a0);
            Atile[sb + 1088] = f2bf(a1);
            Atile[sb + 2176] = f2bf(a2);
        }
    }
    __syncthreads();

    // Phase 2: wave wv = f-tile; B hi/lo frags from pre-tiled, L2-resident Bt.
    int q  = lane >> 4;
    int nn = lane & 15;
    const unsigned short* bt0 = Bth + (((wv * 6) * 4 + q) * 16 + nn) * 8;
    const unsigned short* bt1 = Btl + (((wv * 6) * 4 + q) * 16 + nn) * 8;
    float4v acc = (float4v){0.f, 0.f, 0.f, 0.f};
    #pragma unroll
    for (int ks = 0; ks < 6; ++ks) {
        short8 ah = *(const short8*)&Atile[ks * 544 + q * 136 + nn * 8];
        short8 bh = *(const short8*)(bt0 + ks * 512);
        short8 bl = *(const short8*)(bt1 + ks * 512);
        acc = __builtin_amdgcn_mfma_f32_16x16x32_bf16(ah, bh, acc, 0, 0, 0);
        acc = __builtin_amdgcn_mfma_f32_16x16x32_bf16(ah, bl, acc, 0, 0, 0);
    }
    // D: col f = wv*16+nn, row = t0 + q*4 + r
    #pragma unroll
    for (int r = 0; r < 4; ++r) {
        int row = t0 + q * 4 + r;
        if (row < n_nodes) {
            if (last_layer)
                out[(size_t)row * 64 + wv * 16 + nn] = acc[r];
            else
                hnext[(size_t)row * 64 + wv * 16 + nn] = f2bf(acc[r]);
        }
    }
}

extern "C" void kernel_launch(void* const* d_in, const int* in_sizes, int n_in,
                              void* d_out, int out_size, void* d_ws, size_t ws_size,
                              hipStream_t stream)
{
    const float* feat   = (const float*)d_in[0];   // [N, 64]
    const float* pseudo = (const float*)d_in[1];   // [E, 2]
    const int*   rowptr = (const int*)d_in[2];     // [N+1]
    const int*   colind = (const int*)d_in[3];     // [E]
    const float* projW  = (const float*)d_in[4];   // [L, 2, 2]
    const float* projB  = (const float*)d_in[5];   // [L, 2]
    const float* fcW    = (const float*)d_in[6];   // [L, 64, 192]
    const float* mu     = (const float*)d_in[7];   // [L, 3, 2]
    const float* isg    = (const float*)d_in[8];   // [L, 3, 2]
    float* out = (float*)d_out;

    int n  = in_sizes[0] / FEAT;                        // 50000
    int n_layers = in_sizes[6] / (FEAT * NKERN * FEAT); // 3

    unsigned short* hbA = (unsigned short*)d_ws;                  // n*64
    unsigned short* hbB = hbA + (size_t)n * FEAT;                 // n*64
    unsigned short* Bth = hbB + (size_t)n * FEAT;                 // L*12288
    unsigned short* Btl = Bth + (size_t)n_layers * 12288;         // L*12288

    int n4 = n * FEAT / 4;
    int totalW = n_layers * FEAT * 192;
    int castBlocks = (n4 + 255) / 256;
    int wpBlocks   = (totalW + 255) / 256;

    dim3 blk(256);
    dim3 prepGrid(castBlocks + wpBlocks);
    dim3 layerGrid((n + 15) / 16);
    dim3 layerBlk(256);

    prep_kernel<<<prepGrid, blk, 0, stream>>>(
        feat, hbA, n4, fcW, Bth, Btl, totalW, castBlocks);

    const unsigned short* hin = hbA;
    for (int l = 0; l < n_layers; ++l) {
        int last = (l == n_layers - 1);
        unsigned short* hb_out = (l == 0) ? hbB : hbA;
        layer_kernel<<<layerGrid, layerBlk, 0, stream>>>(
            hin, rowptr, colind, pseudo, projW, projB, mu, isg, l,
            Bth + (size_t)l * 12288, Btl + (size_t)l * 12288,
            out, hb_out, n, last);
        hin = hb_out;
    }
}